// Round 1
// baseline (345.058 us; speedup 1.0000x reference)
//
#include <hip/hip_runtime.h>

typedef float f32x4 __attribute__((ext_vector_type(4)));
typedef short s16x8 __attribute__((ext_vector_type(8)));
typedef unsigned short u16;

#define N_COLS 4096
#define RANK 64

__device__ __forceinline__ unsigned f_asuint(float f) { union { float f; unsigned u; } v; v.f = f; return v.u; }
__device__ __forceinline__ float f_asfloat(unsigned u) { union { unsigned u; float f; } v; v.u = u; return v.f; }
// fp32 -> bf16 round-to-nearest-even
__device__ __forceinline__ short f2bf(float f) {
  unsigned u = f_asuint(f);
  return (short)((u + 0x7fffu + ((u >> 16) & 1u)) >> 16);
}

// ---------------------------------------------------------------------------
// Kernel 0: W[r][n] = b_q[n/64][r] * c_q_t[r][n%64], stored bf16, layout [64][4096]
// ---------------------------------------------------------------------------
__global__ __launch_bounds__(256) void k_prep(const float* __restrict__ b_q,
                                              const float* __restrict__ c_q_t,
                                              u16* __restrict__ W) {
  int idx = blockIdx.x * 256 + threadIdx.x;   // 64*4096 = 262144 total
  int r = idx >> 12;
  int n = idx & 4095;
  float w = b_q[(n >> 6) * RANK + r] * c_q_t[(r << 6) + (n & 63)];
  W[idx] = (u16)f2bf(w);
}

// ---------------------------------------------------------------------------
// Kernel 1: fake-NVFP4 quant of (x*smooth) fused with h2 = xq @ W^T.
// Block = 256 thr (4 waves). Block owns 16 tokens; each wave a 1024-wide K-chunk.
// MFMA 16x16x32 bf16: A = tokens x K (quantized x), B = K x 64 (W), D = 16t x 64r.
// Cross-wave K-partials reduced through LDS, h2 written fp32 [t][64].
// ---------------------------------------------------------------------------
__global__ __launch_bounds__(256) void k_qgemm1(const float* __restrict__ x,
                                                const float* __restrict__ smooth,
                                                const u16* __restrict__ W,
                                                float* __restrict__ h2) {
  const int t0 = blockIdx.x * 16;
  const int wave = threadIdx.x >> 6;
  const int lane = threadIdx.x & 63;
  const int quad = lane >> 4;
  const int tl = lane & 15;
  const int K0 = wave * 1024 + quad * 8;

  const float* xp = x + (size_t)(t0 + tl) * N_COLS + K0;
  const float* sp = smooth + K0;
  const u16* wp0 = W + (size_t)tl * N_COLS + K0;
  const u16* wp1 = wp0 + 16 * N_COLS;
  const u16* wp2 = wp0 + 32 * N_COLS;
  const u16* wp3 = wp0 + 48 * N_COLS;

  f32x4 acc0 = {0.f, 0.f, 0.f, 0.f};
  f32x4 acc1 = {0.f, 0.f, 0.f, 0.f};
  f32x4 acc2 = {0.f, 0.f, 0.f, 0.f};
  f32x4 acc3 = {0.f, 0.f, 0.f, 0.f};

  for (int s = 0; s < 32; ++s) {
    const int o = s * 32;
    float4 xa = *reinterpret_cast<const float4*>(xp + o);
    float4 xb = *reinterpret_cast<const float4*>(xp + o + 4);
    float4 sa = *reinterpret_cast<const float4*>(sp + o);
    float4 sb = *reinterpret_cast<const float4*>(sp + o + 4);
    float xs[8];
    xs[0] = xa.x * sa.x; xs[1] = xa.y * sa.y; xs[2] = xa.z * sa.z; xs[3] = xa.w * sa.w;
    xs[4] = xb.x * sb.x; xs[5] = xb.y * sb.y; xs[6] = xb.z * sb.z; xs[7] = xb.w * sb.w;

    // amax over the 16-block: 8 local + partner half in lane^16 (same token)
    float amax = fabsf(xs[0]);
#pragma unroll
    for (int j = 1; j < 8; ++j) amax = fmaxf(amax, fabsf(xs[j]));
    amax = fmaxf(amax, __shfl_xor(amax, 16));
    float scale = fmaxf(amax * (1.0f / 6.0f), 1e-8f);

    // searchsorted(mids, |y|, 'right') == count(|x| >= mid*scale); round up at ties
    const float th0 = 0.25f * scale, th1 = 0.75f * scale, th2 = 1.25f * scale,
                th3 = 1.75f * scale, th4 = 2.5f * scale, th5 = 3.5f * scale,
                th6 = 5.0f * scale;
    s16x8 af;
#pragma unroll
    for (int j = 0; j < 8; ++j) {
      float ax = fabsf(xs[j]);
      float q = (ax >= th0) ? 0.5f : 0.0f;
      q = (ax >= th1) ? 1.0f : q;
      q = (ax >= th2) ? 1.5f : q;
      q = (ax >= th3) ? 2.0f : q;
      q = (ax >= th4) ? 3.0f : q;
      q = (ax >= th5) ? 4.0f : q;
      q = (ax >= th6) ? 6.0f : q;
      float xq = q * scale;
      xq = f_asfloat(f_asuint(xq) | (f_asuint(xs[j]) & 0x80000000u));
      af[j] = f2bf(xq);
    }

    s16x8 b0 = *reinterpret_cast<const s16x8*>(wp0 + o);
    s16x8 b1 = *reinterpret_cast<const s16x8*>(wp1 + o);
    s16x8 b2 = *reinterpret_cast<const s16x8*>(wp2 + o);
    s16x8 b3 = *reinterpret_cast<const s16x8*>(wp3 + o);

    acc0 = __builtin_amdgcn_mfma_f32_16x16x32_bf16(af, b0, acc0, 0, 0, 0);
    acc1 = __builtin_amdgcn_mfma_f32_16x16x32_bf16(af, b1, acc1, 0, 0, 0);
    acc2 = __builtin_amdgcn_mfma_f32_16x16x32_bf16(af, b2, acc2, 0, 0, 0);
    acc3 = __builtin_amdgcn_mfma_f32_16x16x32_bf16(af, b3, acc3, 0, 0, 0);
  }

  // cross-wave reduction of K-split partials
  __shared__ float red[4 * 16 * 64];
  float* rw = red + wave * 1024 + (quad * 4) * 64 + tl;
#pragma unroll
  for (int reg = 0; reg < 4; ++reg) {
    rw[reg * 64 + 0]  = acc0[reg];
    rw[reg * 64 + 16] = acc1[reg];
    rw[reg * 64 + 32] = acc2[reg];
    rw[reg * 64 + 48] = acc3[reg];
  }
  __syncthreads();
  const float4* r4 = reinterpret_cast<const float4*>(red);
  float4 v0 = r4[threadIdx.x];
  float4 v1 = r4[256 + threadIdx.x];
  float4 v2 = r4[512 + threadIdx.x];
  float4 v3 = r4[768 + threadIdx.x];
  float4 v;
  v.x = v0.x + v1.x + v2.x + v3.x;
  v.y = v0.y + v1.y + v2.y + v3.y;
  v.z = v0.z + v1.z + v2.z + v3.z;
  v.w = v0.w + v1.w + v2.w + v3.w;
  reinterpret_cast<float4*>(h2 + (size_t)t0 * RANK)[threadIdx.x] = v;
}

// ---------------------------------------------------------------------------
// Kernel 2: out[t][m] = bias[m] + h2[t][:] . a_q[m][:]   (K = 64, 2 MFMA steps)
// Block tile 64t x 64m; wave w owns tokens w*16..w*16+15 across all 64 m.
// Epilogue: LDS transpose -> fully coalesced float4 row stores.
// ---------------------------------------------------------------------------
__global__ __launch_bounds__(256) void k_gemm2(const float* __restrict__ h2,
                                               const float* __restrict__ a_q,
                                               const float* __restrict__ bias,
                                               float* __restrict__ out) {
  const int t0 = blockIdx.x * 64;
  const int m0 = blockIdx.y * 64;
  const int wave = threadIdx.x >> 6;
  const int lane = threadIdx.x & 63;
  const int quad = lane >> 4;
  const int tl = lane & 15;

  const float* hp = h2 + (size_t)(t0 + wave * 16 + tl) * RANK + quad * 8;
  const float* ap = a_q + (size_t)(m0 + tl) * RANK + quad * 8;

  f32x4 acc0 = {0.f, 0.f, 0.f, 0.f};
  f32x4 acc1 = {0.f, 0.f, 0.f, 0.f};
  f32x4 acc2 = {0.f, 0.f, 0.f, 0.f};
  f32x4 acc3 = {0.f, 0.f, 0.f, 0.f};

#pragma unroll
  for (int ks = 0; ks < 2; ++ks) {
    const int o = ks * 32;
    float4 ha = *reinterpret_cast<const float4*>(hp + o);
    float4 hb = *reinterpret_cast<const float4*>(hp + o + 4);
    s16x8 af;
    af[0] = f2bf(ha.x); af[1] = f2bf(ha.y); af[2] = f2bf(ha.z); af[3] = f2bf(ha.w);
    af[4] = f2bf(hb.x); af[5] = f2bf(hb.y); af[6] = f2bf(hb.z); af[7] = f2bf(hb.w);

#pragma unroll
    for (int jn = 0; jn < 4; ++jn) {
      const float* a0 = ap + (size_t)jn * 16 * RANK + o;
      float4 ba = *reinterpret_cast<const float4*>(a0);
      float4 bb = *reinterpret_cast<const float4*>(a0 + 4);
      s16x8 bf;
      bf[0] = f2bf(ba.x); bf[1] = f2bf(ba.y); bf[2] = f2bf(ba.z); bf[3] = f2bf(ba.w);
      bf[4] = f2bf(bb.x); bf[5] = f2bf(bb.y); bf[6] = f2bf(bb.z); bf[7] = f2bf(bb.w);
      if (jn == 0) acc0 = __builtin_amdgcn_mfma_f32_16x16x32_bf16(af, bf, acc0, 0, 0, 0);
      if (jn == 1) acc1 = __builtin_amdgcn_mfma_f32_16x16x32_bf16(af, bf, acc1, 0, 0, 0);
      if (jn == 2) acc2 = __builtin_amdgcn_mfma_f32_16x16x32_bf16(af, bf, acc2, 0, 0, 0);
      if (jn == 3) acc3 = __builtin_amdgcn_mfma_f32_16x16x32_bf16(af, bf, acc3, 0, 0, 0);
    }
  }

  __shared__ float tile[64 * 68];  // +4 pad per row, keeps 16B alignment (272B rows)
  float* tw = tile + (wave * 16 + quad * 4) * 68 + tl;
#pragma unroll
  for (int reg = 0; reg < 4; ++reg) {
    tw[reg * 68 + 0]  = acc0[reg];
    tw[reg * 68 + 16] = acc1[reg];
    tw[reg * 68 + 32] = acc2[reg];
    tw[reg * 68 + 48] = acc3[reg];
  }
  __syncthreads();
#pragma unroll
  for (int i = 0; i < 4; ++i) {
    int idx = threadIdx.x + i * 256;   // 1024 float4 = 64x64 tile
    int row = idx >> 4;
    int c = (idx & 15) * 4;
    float4 v = *reinterpret_cast<const float4*>(tile + row * 68 + c);
    float4 b = *reinterpret_cast<const float4*>(bias + m0 + c);
    float4 o;
    o.x = v.x + b.x; o.y = v.y + b.y; o.z = v.z + b.z; o.w = v.w + b.w;
    *reinterpret_cast<float4*>(out + (size_t)(t0 + row) * N_COLS + m0 + c) = o;
  }
}

// ---------------------------------------------------------------------------
extern "C" void kernel_launch(void* const* d_in, const int* in_sizes, int n_in,
                              void* d_out, int out_size, void* d_ws, size_t ws_size,
                              hipStream_t stream) {
  const float* x      = (const float*)d_in[0];
  const float* smooth = (const float*)d_in[1];
  const float* a_q    = (const float*)d_in[2];
  const float* b_q    = (const float*)d_in[3];
  const float* c_q_t  = (const float*)d_in[4];
  const float* bias   = (const float*)d_in[5];
  float* out = (float*)d_out;

  const int T = in_sizes[0] / N_COLS;  // 8192 tokens

  u16* W = (u16*)d_ws;                                     // 64*4096*2   = 512 KB
  float* h2 = (float*)((char*)d_ws + RANK * N_COLS * 2);   // 8192*64*4   = 2 MB

  k_prep<<<(RANK * N_COLS) / 256, 256, 0, stream>>>(b_q, c_q_t, W);
  k_qgemm1<<<T / 16, 256, 0, stream>>>(x, smooth, W, h2);
  dim3 g2(T / 64, N_COLS / 64);
  k_gemm2<<<g2, 256, 0, stream>>>(h2, a_q, bias, out);
}

// Round 3
// 276.246 us; speedup vs baseline: 1.2491x; 1.2491x over previous
//
#include <hip/hip_runtime.h>

typedef float f32x4 __attribute__((ext_vector_type(4)));
typedef short s16x8 __attribute__((ext_vector_type(8)));
typedef short s16x4 __attribute__((ext_vector_type(4)));
typedef unsigned short u16;

#define N_COLS 4096
#define RANK 64

__device__ __forceinline__ unsigned f_asuint(float f) { union { float f; unsigned u; } v; v.f = f; return v.u; }
__device__ __forceinline__ float f_asfloat(unsigned u) { union { unsigned u; float f; } v; v.u = u; return v.f; }
// fp32 -> bf16 round-to-nearest-even
__device__ __forceinline__ short f2bf(float f) {
  unsigned u = f_asuint(f);
  return (short)((u + 0x7fffu + ((u >> 16) & 1u)) >> 16);
}

// ---------------------------------------------------------------------------
// Kernel 0: W[r][n] = b_q[n/64][r] * c_q_t[r][n%64] (bf16, [64][4096])
//           a_bf[m][r] = bf16(a_q[m][r])            (bf16, [4096][64])
// ---------------------------------------------------------------------------
__global__ __launch_bounds__(256) void k_prep(const float* __restrict__ b_q,
                                              const float* __restrict__ c_q_t,
                                              const float* __restrict__ a_q,
                                              u16* __restrict__ W,
                                              u16* __restrict__ a_bf) {
  int idx = blockIdx.x * 256 + threadIdx.x;   // 2*262144 total
  if (idx < RANK * N_COLS) {
    int r = idx >> 12;
    int n = idx & 4095;
    W[idx] = (u16)f2bf(b_q[(n >> 6) * RANK + r] * c_q_t[(r << 6) + (n & 63)]);
  } else {
    int j = idx - RANK * N_COLS;
    a_bf[j] = (u16)f2bf(a_q[j]);
  }
}

// ---------------------------------------------------------------------------
// Kernel 1: fake-NVFP4 quant of (x*smooth) fused with h2 = xq @ W^T.
// Block = 512 thr (8 waves). Block owns 16 tokens; wave w owns K-chunk of 512.
// Cross-wave K-partials reduced via LDS, h2 stored bf16 [t][64].
// ---------------------------------------------------------------------------
__global__ __launch_bounds__(512, 4) void k_qgemm1(const float* __restrict__ x,
                                                   const float* __restrict__ smooth,
                                                   const u16* __restrict__ W,
                                                   u16* __restrict__ h2b) {
  const int t0 = blockIdx.x * 16;
  const int wave = threadIdx.x >> 6;   // 0..7
  const int lane = threadIdx.x & 63;
  const int quad = lane >> 4;
  const int tl = lane & 15;
  const int K0 = wave * 512 + quad * 8;

  const float* xp = x + (size_t)(t0 + tl) * N_COLS + K0;
  const float* sp = smooth + K0;
  const u16* wp0 = W + (size_t)tl * N_COLS + K0;
  const u16* wp1 = wp0 + 16 * N_COLS;
  const u16* wp2 = wp0 + 32 * N_COLS;
  const u16* wp3 = wp0 + 48 * N_COLS;

  f32x4 acc0 = {0.f, 0.f, 0.f, 0.f};
  f32x4 acc1 = {0.f, 0.f, 0.f, 0.f};
  f32x4 acc2 = {0.f, 0.f, 0.f, 0.f};
  f32x4 acc3 = {0.f, 0.f, 0.f, 0.f};

  for (int s = 0; s < 16; ++s) {
    const int o = s * 32;
    f32x4 xa = __builtin_nontemporal_load(reinterpret_cast<const f32x4*>(xp + o));
    f32x4 xb = __builtin_nontemporal_load(reinterpret_cast<const f32x4*>(xp + o + 4));
    f32x4 sa = *reinterpret_cast<const f32x4*>(sp + o);
    f32x4 sb = *reinterpret_cast<const f32x4*>(sp + o + 4);
    float xs[8];
    xs[0] = xa.x * sa.x; xs[1] = xa.y * sa.y; xs[2] = xa.z * sa.z; xs[3] = xa.w * sa.w;
    xs[4] = xb.x * sb.x; xs[5] = xb.y * sb.y; xs[6] = xb.z * sb.z; xs[7] = xb.w * sb.w;

    // amax over the 16-block: 8 local + partner half in lane^16 (same token)
    float amax = fabsf(xs[0]);
#pragma unroll
    for (int j = 1; j < 8; ++j) amax = fmaxf(amax, fabsf(xs[j]));
    amax = fmaxf(amax, __shfl_xor(amax, 16));
    float scale = fmaxf(amax * (1.0f / 6.0f), 1e-8f);

    // searchsorted(mids, |y|, 'right') == count(|x| >= mid*scale)
    const float th0 = 0.25f * scale, th1 = 0.75f * scale, th2 = 1.25f * scale,
                th3 = 1.75f * scale, th4 = 2.5f * scale, th5 = 3.5f * scale,
                th6 = 5.0f * scale;
    s16x8 af;
#pragma unroll
    for (int j = 0; j < 8; ++j) {
      float ax = fabsf(xs[j]);
      float q = (ax >= th0) ? 0.5f : 0.0f;
      q = (ax >= th1) ? 1.0f : q;
      q = (ax >= th2) ? 1.5f : q;
      q = (ax >= th3) ? 2.0f : q;
      q = (ax >= th4) ? 3.0f : q;
      q = (ax >= th5) ? 4.0f : q;
      q = (ax >= th6) ? 6.0f : q;
      float xq = q * scale;
      xq = f_asfloat(f_asuint(xq) | (f_asuint(xs[j]) & 0x80000000u));
      af[j] = f2bf(xq);
    }

    s16x8 b0 = *reinterpret_cast<const s16x8*>(wp0 + o);
    s16x8 b1 = *reinterpret_cast<const s16x8*>(wp1 + o);
    s16x8 b2 = *reinterpret_cast<const s16x8*>(wp2 + o);
    s16x8 b3 = *reinterpret_cast<const s16x8*>(wp3 + o);

    acc0 = __builtin_amdgcn_mfma_f32_16x16x32_bf16(af, b0, acc0, 0, 0, 0);
    acc1 = __builtin_amdgcn_mfma_f32_16x16x32_bf16(af, b1, acc1, 0, 0, 0);
    acc2 = __builtin_amdgcn_mfma_f32_16x16x32_bf16(af, b2, acc2, 0, 0, 0);
    acc3 = __builtin_amdgcn_mfma_f32_16x16x32_bf16(af, b3, acc3, 0, 0, 0);
  }

  // cross-wave reduction of 8 K-split partials
  __shared__ float red[8 * 16 * 64];   // 32 KB
  float* rw = red + wave * 1024 + (quad * 4) * 64 + tl;
#pragma unroll
  for (int reg = 0; reg < 4; ++reg) {
    rw[reg * 64 + 0]  = acc0[reg];
    rw[reg * 64 + 16] = acc1[reg];
    rw[reg * 64 + 32] = acc2[reg];
    rw[reg * 64 + 48] = acc3[reg];
  }
  __syncthreads();
  if (threadIdx.x < 256) {
    const f32x4* r4 = reinterpret_cast<const f32x4*>(red);
    f32x4 v = r4[threadIdx.x];
#pragma unroll
    for (int p = 1; p < 8; ++p) {
      f32x4 u = r4[p * 256 + threadIdx.x];
      v.x += u.x; v.y += u.y; v.z += u.z; v.w += u.w;
    }
    int t = threadIdx.x >> 4;          // token 0..15
    int rr = (threadIdx.x & 15) * 4;   // r offset
    s16x4 o4;
    o4.x = f2bf(v.x); o4.y = f2bf(v.y); o4.z = f2bf(v.z); o4.w = f2bf(v.w);
    *reinterpret_cast<s16x4*>(h2b + (size_t)(t0 + t) * RANK + rr) = o4;
  }
}

// ---------------------------------------------------------------------------
// Kernel 2: out[t][m] = bias[m] + h2[t][:] . a_bf[m][:]   (K = 64)
// Block tile 32t x 256m, grid m-fastest so co-resident blocks cover contiguous
// row bands. Wave w owns m-strip w*64. Epilogue: chunked LDS transpose ->
// fully contiguous 1 KB row-segment nontemporal stores.
// ---------------------------------------------------------------------------
__global__ __launch_bounds__(256, 4) void k_gemm2(const u16* __restrict__ h2b,
                                                  const u16* __restrict__ a_bf,
                                                  const float* __restrict__ bias,
                                                  float* __restrict__ out) {
  const int t0 = blockIdx.y * 32;
  const int m0 = blockIdx.x * 256;
  const int wave = threadIdx.x >> 6;
  const int lane = threadIdx.x & 63;
  const int quad = lane >> 4;
  const int tl = lane & 15;

  const u16* hp0 = h2b + (size_t)(t0 + tl) * RANK + quad * 8;
  const u16* hp1 = hp0 + 16 * RANK;
  const u16* ap = a_bf + (size_t)(m0 + wave * 64 + tl) * RANK + quad * 8;

  f32x4 acc[2][4] = {};

#pragma unroll
  for (int o = 0; o < 64; o += 32) {
    s16x8 a0 = *reinterpret_cast<const s16x8*>(hp0 + o);
    s16x8 a1 = *reinterpret_cast<const s16x8*>(hp1 + o);
#pragma unroll
    for (int mg = 0; mg < 4; ++mg) {
      s16x8 bfr = *reinterpret_cast<const s16x8*>(ap + (size_t)mg * 16 * RANK + o);
      acc[0][mg] = __builtin_amdgcn_mfma_f32_16x16x32_bf16(a0, bfr, acc[0][mg], 0, 0, 0);
      acc[1][mg] = __builtin_amdgcn_mfma_f32_16x16x32_bf16(a1, bfr, acc[1][mg], 0, 0, 0);
    }
  }

  // 16t x 256m staging buffer; row stride 260 floats (1040 B, 16B-aligned,
  // write conflicts collapse to free 2-way)
  __shared__ float tile[16 * 260];
#pragma unroll
  for (int tg = 0; tg < 2; ++tg) {
    if (tg) __syncthreads();
#pragma unroll
    for (int mg = 0; mg < 4; ++mg)
#pragma unroll
      for (int reg = 0; reg < 4; ++reg)
        tile[(quad * 4 + reg) * 260 + wave * 64 + mg * 16 + tl] = acc[tg][mg][reg];
    __syncthreads();
#pragma unroll
    for (int i = 0; i < 4; ++i) {
      int idx = threadIdx.x + i * 256;   // 1024 float4 = 16 x 256 chunk
      int row = idx >> 6;
      int c4 = (idx & 63) << 2;
      f32x4 v = *reinterpret_cast<const f32x4*>(tile + row * 260 + c4);
      f32x4 b = *reinterpret_cast<const f32x4*>(bias + m0 + c4);
      f32x4 ov;
      ov.x = v.x + b.x; ov.y = v.y + b.y; ov.z = v.z + b.z; ov.w = v.w + b.w;
      __builtin_nontemporal_store(ov,
        reinterpret_cast<f32x4*>(out + (size_t)(t0 + tg * 16 + row) * N_COLS + m0 + c4));
    }
  }
}

// ---------------------------------------------------------------------------
extern "C" void kernel_launch(void* const* d_in, const int* in_sizes, int n_in,
                              void* d_out, int out_size, void* d_ws, size_t ws_size,
                              hipStream_t stream) {
  const float* x      = (const float*)d_in[0];
  const float* smooth = (const float*)d_in[1];
  const float* a_q    = (const float*)d_in[2];
  const float* b_q    = (const float*)d_in[3];
  const float* c_q_t  = (const float*)d_in[4];
  const float* bias   = (const float*)d_in[5];
  float* out = (float*)d_out;

  const int T = in_sizes[0] / N_COLS;  // 8192 tokens

  u16* W    = (u16*)d_ws;                                   // 512 KB
  u16* a_bf = (u16*)((char*)d_ws + 524288);                 // 512 KB
  u16* h2b  = (u16*)((char*)d_ws + 1048576);                // T*64*2 = 1 MB

  k_prep<<<2048, 256, 0, stream>>>(b_q, c_q_t, a_q, W, a_bf);
  k_qgemm1<<<T / 16, 512, 0, stream>>>(x, smooth, W, h2b);
  dim3 g2(N_COLS / 256, T / 32);
  k_gemm2<<<g2, 256, 0, stream>>>(h2b, a_bf, bias, out);
}